// Round 7
// baseline (593.955 us; speedup 1.0000x reference)
//
#include <hip/hip_runtime.h>
#include <hip/hip_bf16.h>

#define H 1024
#define E 1024
#define VOCAB 50257
#define M 16384

#define NBLK 256
#define NTHR 1024
#define FC1_CHUNKS ((VOCAB + 15) / 16)        // 3142 chunks of 16 rows
#define FC1_ROUNDS ((FC1_CHUNKS + NBLK - 1) / NBLK)   // 13

__device__ __forceinline__ float sigmoidf_(float x) { return 1.0f / (1.0f + expf(-x)); }

__device__ __forceinline__ float wave_sum(float v) {
    #pragma unroll
    for (int o = 32; o > 0; o >>= 1) v += __shfl_down(v, o);
    return v;
}

// zero barrier + counter slots each call (graph-replay safe)
__global__ void k_init(unsigned* __restrict__ bar) {
    if (threadIdx.x < 8) bar[threadIdx.x] = 0u;
}

// device-scope grid barrier: 256 resident blocks (1/CU guaranteed)
__device__ __forceinline__ void gridbar(unsigned* bar, int idx) {
    __threadfence();                          // release my writes
    __syncthreads();
    if (threadIdx.x == 0) {
        __hip_atomic_fetch_add(&bar[idx], 1u, __ATOMIC_RELEASE, __HIP_MEMORY_SCOPE_AGENT);
        while (__hip_atomic_load(&bar[idx], __ATOMIC_ACQUIRE, __HIP_MEMORY_SCOPE_AGENT) < NBLK)
            __builtin_amdgcn_s_sleep(8);
    }
    __syncthreads();
    __threadfence();                          // acquire side
}

__global__ __launch_bounds__(NTHR, 4) void k_mega(
    const int* __restrict__ x, const float* __restrict__ emb,
    const float* __restrict__ W_ih, const float* __restrict__ W_hh,
    const float* __restrict__ b_ih, const float* __restrict__ b_hh,
    const float* __restrict__ h0, const float* __restrict__ c0,
    const float* __restrict__ hem, const float* __restrict__ Ws_w,
    const float* __restrict__ Wz_w, const float* __restrict__ Wz_b,
    const float* __restrict__ W2_w, const float* __restrict__ W2_b,
    const float* __restrict__ W1_w, const float* __restrict__ W1_b,
    float* __restrict__ out, float* __restrict__ zout, float* __restrict__ pv,
    float* __restrict__ h, float* __restrict__ v, float* __restrict__ sc,
    float* __restrict__ dv, float* __restrict__ oh,
    float* __restrict__ Mb, float* __restrict__ Sb, float* __restrict__ db,
    unsigned* __restrict__ bar) {
    int b = blockIdx.x, t = threadIdx.x;
    int w = t >> 6, lane = t & 63;

    // ================= phase A: LSTM, 4 hidden units per block =================
    if (t < 4) { v[4 * b + t] = 0.f; dv[4 * b + t] = 0.f; }
    __shared__ int h0nz;
    if (t == 0) h0nz = 0;
    __syncthreads();
    if (t < 256) {                            // runtime all-zero check on h0 (4 KB)
        float4 q = ((const float4*)h0)[t];
        if (q.x != 0.f || q.y != 0.f || q.z != 0.f || q.w != 0.f) h0nz = 1;
    }
    __syncthreads();
    __shared__ float gs[4][4];                // [unit][gate]
    {
        int jj = w >> 2, g = w & 3;           // 4 units x 4 gates = 16 waves
        int j = 4 * b + jj;
        int r = g * H + j;
        const float4* A  = (const float4*)(W_ih + (size_t)r * E);
        const float4* xe = (const float4*)(emb + (size_t)x[0] * E);
        float acc = 0.f;
        #pragma unroll
        for (int i = 0; i < 4; i++) {
            int idx = lane + 64 * i;
            float4 a = A[idx], xv = xe[idx];
            acc += a.x * xv.x + a.y * xv.y + a.z * xv.z + a.w * xv.w;
        }
        if (h0nz) {
            const float4* Bm = (const float4*)(W_hh + (size_t)r * H);
            const float4* hp = (const float4*)h0;
            #pragma unroll
            for (int i = 0; i < 4; i++) {
                int idx = lane + 64 * i;
                float4 bb = Bm[idx], hv = hp[idx];
                acc += bb.x * hv.x + bb.y * hv.y + bb.z * hv.z + bb.w * hv.w;
            }
        }
        acc = wave_sum(acc);
        if (lane == 0) gs[jj][g] = acc + b_ih[r] + b_hh[r];
    }
    __syncthreads();
    if (t < 4) {
        int j = 4 * b + t;
        float c = sigmoidf_(gs[t][1]) * c0[j] + sigmoidf_(gs[t][0]) * tanhf(gs[t][2]);
        h[j] = sigmoidf_(gs[t][3]) * tanhf(c);
    }
    gridbar(bar, 0);

    // ================= phase B: fc2 (4 rows, waves 0-3) + hWs (4 rows, all thr) ====
    if (w < 4) {                              // oh[j] = tanh(h.(W2_l+W2_r)+b)
        int j = 4 * b + w;
        const float4* R  = (const float4*)(W2_w + (size_t)j * 2 * H);
        const float4* H4 = (const float4*)h;
        float acc = 0.f;
        #pragma unroll
        for (int i = 0; i < 4; i++) {
            int idx = lane + 64 * i;
            float4 hv = H4[idx];
            float4 a = R[idx];
            float4 bb = R[256 + idx];
            acc += hv.x * (a.x + bb.x) + hv.y * (a.y + bb.y)
                 + hv.z * (a.z + bb.z) + hv.w * (a.w + bb.w);
        }
        acc = wave_sum(acc);
        if (lane == 0) oh[j] = tanhf(acc + W2_b[j]);
    }
    {
        __shared__ float hs[4];
        if (t < 4) hs[t] = h[4 * b + t];
        __syncthreads();
        float acc = 0.f;
        #pragma unroll
        for (int jj = 0; jj < 4; jj++)
            acc += hs[jj] * Ws_w[(size_t)(4 * b + jj) * H + t];
        atomicAdd(&v[t], acc);                // Ws_b dropped: uniform softmax shift
    }
    gridbar(bar, 1);

    // ================= phase C: attn partials — R4-proven body =================
    {
        __shared__ float s_sc[16];
        int m0 = b * 64;
        const float4* V4 = (const float4*)v;
        float run_m = -1e30f, run_s = 0.f, acc = 0.f;
        #pragma unroll
        for (int chunk = 0; chunk < 4; chunk++) {
            int row = m0 + chunk * 16 + w;
            const float4* A = (const float4*)(hem + (size_t)row * H);
            float d = 0.f;
            #pragma unroll
            for (int i = 0; i < 4; i++) {
                float4 a = A[lane + 64 * i], bb = V4[lane + 64 * i];
                d += a.x * bb.x + a.y * bb.y + a.z * bb.z + a.w * bb.w;
            }
            d = wave_sum(d);
            if (lane == 0) { s_sc[w] = d; sc[row] = d; }
            __syncthreads();
            float cmax = s_sc[0];
            #pragma unroll
            for (int rr = 1; rr < 16; rr++) cmax = fmaxf(cmax, s_sc[rr]);
            float new_m = fmaxf(run_m, cmax);
            float scale = expf(run_m - new_m);
            run_s *= scale; acc *= scale;
            #pragma unroll
            for (int rr = 0; rr < 16; rr++) {
                float e = expf(s_sc[rr] - new_m);
                run_s += e;
                acc += e * hem[(size_t)(m0 + chunk * 16 + rr) * H + t];
            }
            run_m = new_m;
            __syncthreads();
        }
        db[(size_t)b * H + t] = acc;
        if (t == 0) { Mb[b] = run_m; Sb[b] = run_s; }
    }
    gridbar(bar, 2);

    // ================= phase D: combine (blocks 240-255) + fc1 (all blocks) =====
    if (b >= NBLK - 16) {                     // these blocks get 12 fc1 chunks, not 13
        int b2 = b - (NBLK - 16);             // 0..15
        bool act = (t < 256);
        __shared__ float s[256];
        __shared__ float s_w[16];
        __shared__ unsigned s_old;
        float mval = act ? Mb[t] : -1e30f;
        if (act) s[t] = mval;
        __syncthreads();
        for (int o = 128; o > 0; o >>= 1) {
            if (act && t < o) s[t] = fmaxf(s[t], s[t + o]);
            __syncthreads();
        }
        float gmax = s[0];
        __syncthreads();
        if (act) s[t] = Sb[t] * expf(mval - gmax);
        __syncthreads();
        for (int o = 128; o > 0; o >>= 1) {
            if (act && t < o) s[t] += s[t + o];
            __syncthreads();
        }
        float inv = 1.f / s[0];
        __syncthreads();
        if (act) {
            int base = b2 * 1024;
            #pragma unroll
            for (int q = 0; q < 4; q++) {
                int i = base + t + 256 * q;
                pv[i] = expf(sc[i] - gmax) * inv;
            }
        }
        if (t < 16) s_w[t] = expf(Mb[b2 * 16 + t] - gmax) * inv;
        __syncthreads();
        if (act) {
            float a0 = 0.f, a1 = 0.f, a2 = 0.f, a3 = 0.f;
            #pragma unroll
            for (int rr = 0; rr < 16; rr++) {
                const float* row = db + (size_t)(b2 * 16 + rr) * H;
                float wr = s_w[rr];
                a0 += wr * row[t];       a1 += wr * row[t + 256];
                a2 += wr * row[t + 512]; a3 += wr * row[t + 768];
            }
            atomicAdd(&dv[t], a0);       atomicAdd(&dv[t + 256], a1);
            atomicAdd(&dv[t + 512], a2); atomicAdd(&dv[t + 768], a3);
        }
        __threadfence();
        if (t == 0) s_old = atomicAdd(&bar[4], 1u);
        __syncthreads();
        if (s_old == 15u) {                   // last combine block computes z
            __threadfence();
            float acc = 0.f;
            if (act) for (int i = t; i < H; i += 256)
                acc += h[i] * Wz_w[i] + dv[i] * Wz_w[H + i];
            if (act) s[t] = acc;
            __syncthreads();
            for (int o = 128; o > 0; o >>= 1) {
                if (act && t < o) s[t] += s[t + o];
                __syncthreads();
            }
            if (t == 0) zout[0] = sigmoidf_(s[0] + Wz_b[0]);
        }
    }
    // fc1: static interleaved chunks, wave per row
    {
        const float4* O4 = (const float4*)oh;
        float4 o0 = O4[lane], o1 = O4[lane + 64], o2 = O4[lane + 128], o3 = O4[lane + 192];
        for (int round = 0; round < FC1_ROUNDS; round++) {
            int chunk = round * NBLK + b;
            if (chunk >= FC1_CHUNKS) break;
            int r = chunk * 16 + w;
            if (r >= VOCAB) continue;
            const float4* A = (const float4*)(W1_w + (size_t)r * H);
            float acc = 0.f;
            #pragma unroll
            for (int i = 0; i < 4; i++) {
                int idx = lane + 64 * i;
                float4 a = A[idx];
                float4 ov = (i == 0) ? o0 : (i == 1) ? o1 : (i == 2) ? o2 : o3;
                acc += a.x * ov.x + a.y * ov.y + a.z * ov.z + a.w * ov.w;
            }
            acc = wave_sum(acc);
            if (lane == 0) out[r] = acc + W1_b[r];
        }
    }
}

extern "C" void kernel_launch(void* const* d_in, const int* in_sizes, int n_in,
                              void* d_out, int out_size, void* d_ws, size_t ws_size,
                              hipStream_t stream) {
    const int*   x      = (const int*)  d_in[0];
    // d_in[1] entity_target: unused — new_mem[t] == h, scatter elides
    const float* emb    = (const float*)d_in[2];
    const float* W_ih   = (const float*)d_in[3];
    const float* W_hh   = (const float*)d_in[4];
    const float* b_ih   = (const float*)d_in[5];
    const float* b_hh   = (const float*)d_in[6];
    const float* h0     = (const float*)d_in[7];
    const float* c0     = (const float*)d_in[8];
    const float* hem    = (const float*)d_in[9];
    const float* Ws_w   = (const float*)d_in[10];
    // d_in[11] Ws_b: uniform shift of all scores — cancels in softmax
    const float* Wz_w   = (const float*)d_in[12];
    const float* Wz_b   = (const float*)d_in[13];
    const float* W2_w   = (const float*)d_in[14];
    const float* W2_b   = (const float*)d_in[15];
    const float* W1_w   = (const float*)d_in[16];
    const float* W1_b   = (const float*)d_in[17];

    float* out  = (float*)d_out;              // logits [V]
    float* zout = out + VOCAB;                // z_i    [1]
    float* pv   = out + VOCAB + 1;            // p_v    [M]

    float* ws = (float*)d_ws;
    float* h   = ws;                  // 1024
    float* v   = ws + 1024;           // 1024 (atomic acc, zeroed phase A)
    float* sc  = ws + 2048;           // 16384
    float* dv  = ws + 18432;          // 1024 (atomic acc, zeroed phase A)
    float* oh  = ws + 19456;          // 1024
    float* Mb  = ws + 20480;          // 256
    float* Sb  = ws + 20736;          // 256
    float* db  = ws + 21504;          // 256*1024 partial d vectors
    unsigned* bar = (unsigned*)(ws + 21504 + 262144);  // 8 uints (zeroed by k_init)

    k_init<<<1, 64, 0, stream>>>(bar);
    k_mega<<<NBLK, NTHR, 0, stream>>>(x, emb, W_ih, W_hh, b_ih, b_hh, h0, c0,
                                      hem, Ws_w, Wz_w, Wz_b, W2_w, W2_b, W1_w, W1_b,
                                      out, zout, pv, h, v, sc, dv, oh, Mb, Sb, db, bar);
}

// Round 8
// 77.065 us; speedup vs baseline: 7.7072x; 7.7072x over previous
//
#include <hip/hip_runtime.h>
#include <hip/hip_bf16.h>

#define H 1024
#define E 1024
#define VOCAB 50257
#define M 16384

#define COMB_BLOCKS 16
#define FC1_ROWS_PER_BLOCK 8                  // 256 thr, 2 rows per wave
#define FC1_BLOCKS ((VOCAB + FC1_ROWS_PER_BLOCK - 1) / FC1_ROWS_PER_BLOCK)   // 6283

__device__ __forceinline__ float sigmoidf_(float x) { return 1.0f / (1.0f + expf(-x)); }

__device__ __forceinline__ float wave_sum(float v) {
    #pragma unroll
    for (int o = 32; o > 0; o >>= 1) v += __shfl_down(v, o);
    return v;
}

// ---------------- K1: LSTM + zero accumulators/counters (R4-proven) ----------------
// grid 1024 (block per hidden unit j), 256 thr (4 waves = gates i,f,g,o).
// Runtime check: if h0 is all-zero, skip the W_hh matvec (16.8 MB).
__global__ void k_lstm(const int* __restrict__ x, const float* __restrict__ emb,
                       const float* __restrict__ W_ih, const float* __restrict__ W_hh,
                       const float* __restrict__ b_ih, const float* __restrict__ b_hh,
                       const float* __restrict__ h0, const float* __restrict__ c0,
                       float* __restrict__ h_out, float* __restrict__ v_z,
                       float* __restrict__ dv_z, unsigned int* __restrict__ cnt) {
    int j = blockIdx.x;
    if (threadIdx.x == 0) {
        v_z[j] = 0.f; dv_z[j] = 0.f;
        if (j == 0) { cnt[0] = 0u; cnt[1] = 0u; }
    }
    __shared__ int h0nz;
    if (threadIdx.x == 0) h0nz = 0;
    __syncthreads();
    {   // 256 threads cover all 1024 floats of h0 (4 KB, cache-hot)
        float4 t = ((const float4*)h0)[threadIdx.x];
        if (t.x != 0.f || t.y != 0.f || t.z != 0.f || t.w != 0.f) h0nz = 1;
    }
    __syncthreads();
    int w = threadIdx.x >> 6;
    int lane = threadIdx.x & 63;
    int r = w * H + j;                       // gate rows: i=j, f=H+j, g=2H+j, o=3H+j
    const float4* A  = (const float4*)(W_ih + (size_t)r * E);
    const float4* xe = (const float4*)(emb + (size_t)x[0] * E);
    float acc = 0.f;
    #pragma unroll
    for (int i = 0; i < 4; i++) {
        int idx = lane + 64 * i;
        float4 a = A[idx], xv = xe[idx];
        acc += a.x * xv.x + a.y * xv.y + a.z * xv.z + a.w * xv.w;
    }
    if (h0nz) {
        const float4* Bm = (const float4*)(W_hh + (size_t)r * H);
        const float4* hp = (const float4*)h0;
        #pragma unroll
        for (int i = 0; i < 4; i++) {
            int idx = lane + 64 * i;
            float4 b = Bm[idx], hv = hp[idx];
            acc += b.x * hv.x + b.y * hv.y + b.z * hv.z + b.w * hv.w;
        }
    }
    acc = wave_sum(acc);
    __shared__ float g[4];
    if (lane == 0) g[w] = acc + b_ih[r] + b_hh[r];
    __syncthreads();
    if (threadIdx.x == 0) {
        float c = sigmoidf_(g[1]) * c0[j] + sigmoidf_(g[0]) * tanhf(g[2]);
        h_out[j] = sigmoidf_(g[3]) * tanhf(c);
    }
}

// ---------------- K2: fc2 (oh) + hWs (v), both need only h (R4-proven) ----------------
__global__ void k_mid(const float* __restrict__ h,
                      const float* __restrict__ W2_w, const float* __restrict__ W2_b,
                      float* __restrict__ oh,
                      const float* __restrict__ Ws_w, float* __restrict__ v) {
    if (blockIdx.x < 256) {                  // fc2: oh[j] = tanh(h.(W2_l+W2_r)+b)
        int j = blockIdx.x * 4 + (threadIdx.x >> 6);
        int lane = threadIdx.x & 63;
        const float4* R  = (const float4*)(W2_w + (size_t)j * 2 * H);
        const float4* H4 = (const float4*)h;
        float acc = 0.f;
        #pragma unroll
        for (int i = 0; i < 4; i++) {
            int idx = lane + 64 * i;
            float4 hv = H4[idx];
            float4 a = R[idx];
            float4 b = R[256 + idx];
            acc += hv.x * (a.x + b.x) + hv.y * (a.y + b.y)
                 + hv.z * (a.z + b.z) + hv.w * (a.w + b.w);
        }
        acc = wave_sum(acc);
        if (lane == 0) oh[j] = tanhf(acc + W2_b[j]);
        return;
    }
    // hWs: v[k] += sum_j h[j]*Ws_w[j][k]   (Ws_b dropped: uniform softmax shift)
    int j0 = (blockIdx.x - 256) * 16;
    int t = threadIdx.x;                     // float4 column 0..255
    __shared__ float hs[16];
    if (t < 16) hs[t] = h[j0 + t];
    __syncthreads();
    float4 acc = {0.f, 0.f, 0.f, 0.f};
    #pragma unroll
    for (int jj = 0; jj < 16; jj++) {
        float4 wv = ((const float4*)(Ws_w + (size_t)(j0 + jj) * H))[t];
        float hj = hs[jj];
        acc.x += hj * wv.x; acc.y += hj * wv.y; acc.z += hj * wv.z; acc.w += hj * wv.w;
    }
    atomicAdd(&v[4 * t + 0], acc.x); atomicAdd(&v[4 * t + 1], acc.y);
    atomicAdd(&v[4 * t + 2], acc.z); atomicAdd(&v[4 * t + 3], acc.w);
}

// ---------------- K3: single-HBM-pass online attention partials (R4-proven) --------
__global__ void k_attn(const float* __restrict__ hem, const float* __restrict__ v,
                       float* __restrict__ sc, float* __restrict__ db,
                       float* __restrict__ Mb, float* __restrict__ Sb) {
    __shared__ float s_sc[16];
    int b = blockIdx.x;
    int m0 = b * 64;
    int w = threadIdx.x >> 6, lane = threadIdx.x & 63;
    int t = threadIdx.x;
    const float4* V4 = (const float4*)v;
    float run_m = -1e30f, run_s = 0.f, acc = 0.f;
    #pragma unroll
    for (int chunk = 0; chunk < 4; chunk++) {
        int row = m0 + chunk * 16 + w;
        const float4* A = (const float4*)(hem + (size_t)row * H);
        float d = 0.f;
        #pragma unroll
        for (int i = 0; i < 4; i++) {
            float4 a = A[lane + 64 * i], bb = V4[lane + 64 * i];
            d += a.x * bb.x + a.y * bb.y + a.z * bb.z + a.w * bb.w;
        }
        d = wave_sum(d);
        if (lane == 0) { s_sc[w] = d; sc[row] = d; }
        __syncthreads();
        float cmax = s_sc[0];
        #pragma unroll
        for (int rr = 1; rr < 16; rr++) cmax = fmaxf(cmax, s_sc[rr]);
        float new_m = fmaxf(run_m, cmax);
        float scale = expf(run_m - new_m);
        run_s *= scale; acc *= scale;
        #pragma unroll
        for (int rr = 0; rr < 16; rr++) {
            float e = expf(s_sc[rr] - new_m);
            run_s += e;
            acc += e * hem[(size_t)(m0 + chunk * 16 + rr) * H + t];
        }
        run_m = new_m;
        __syncthreads();
    }
    db[(size_t)b * H + t] = acc;
    if (t == 0) { Mb[b] = run_m; Sb[b] = run_s; }
}

// ---------------- K4: combine(+z) + fc1 in one launch ----------------
// blocks [0,16): softmax combine -> pv, dv(atomic); last (cnt[1]) -> z.
// blocks [16, 16+FC1_BLOCKS): fc1, 2 rows per wave (8/block) — 8 loads in flight.
__global__ void k_fc1comb(const float* __restrict__ oh, const float* __restrict__ W1_w,
                          const float* __restrict__ W1_b, float* __restrict__ out,
                          const float* __restrict__ sc, const float* __restrict__ db,
                          const float* __restrict__ Mb, const float* __restrict__ Sb,
                          float* __restrict__ pv, float* __restrict__ dv,
                          const float* __restrict__ h,
                          const float* __restrict__ Wz_w, const float* __restrict__ Wz_b,
                          float* __restrict__ zout, unsigned int* __restrict__ cnt) {
    if (blockIdx.x < COMB_BLOCKS) {
        int b2 = blockIdx.x;                 // 0..15
        int t = threadIdx.x;                 // 0..255
        __shared__ float s[256];
        __shared__ float s_w[16];
        __shared__ unsigned int s_old;
        float mval = Mb[t];
        s[t] = mval; __syncthreads();
        for (int o = 128; o > 0; o >>= 1) { if (t < o) s[t] = fmaxf(s[t], s[t + o]); __syncthreads(); }
        float gmax = s[0]; __syncthreads();
        s[t] = Sb[t] * expf(mval - gmax); __syncthreads();
        for (int o = 128; o > 0; o >>= 1) { if (t < o) s[t] += s[t + o]; __syncthreads(); }
        float inv = 1.f / s[0]; __syncthreads();
        int base = b2 * 1024;
        #pragma unroll
        for (int q = 0; q < 4; q++) {
            int i = base + t + 256 * q;
            pv[i] = expf(sc[i] - gmax) * inv;
        }
        if (t < 16) s_w[t] = expf(Mb[b2 * 16 + t] - gmax) * inv;
        __syncthreads();
        float a0 = 0.f, a1 = 0.f, a2 = 0.f, a3 = 0.f;
        #pragma unroll
        for (int rr = 0; rr < 16; rr++) {
            const float* row = db + (size_t)(b2 * 16 + rr) * H;
            float wr = s_w[rr];
            a0 += wr * row[t];       a1 += wr * row[t + 256];
            a2 += wr * row[t + 512]; a3 += wr * row[t + 768];
        }
        atomicAdd(&dv[t], a0);       atomicAdd(&dv[t + 256], a1);
        atomicAdd(&dv[t + 512], a2); atomicAdd(&dv[t + 768], a3);
        __threadfence();
        if (t == 0) s_old = atomicAdd(&cnt[1], 1u);
        __syncthreads();
        if (s_old == COMB_BLOCKS - 1) {      // last combine block computes z
            __threadfence();
            float acc = 0.f;
            for (int i = t; i < H; i += 256) acc += h[i] * Wz_w[i] + dv[i] * Wz_w[H + i];
            s[t] = acc; __syncthreads();
            for (int o = 128; o > 0; o >>= 1) { if (t < o) s[t] += s[t + o]; __syncthreads(); }
            if (t == 0) zout[0] = sigmoidf_(s[0] + Wz_b[0]);
        }
        return;
    }
    // fc1: 2 rows per wave -> 8 independent loads in flight, ~40 VGPR (no spill)
    int rbase = (blockIdx.x - COMB_BLOCKS) * FC1_ROWS_PER_BLOCK + (threadIdx.x >> 6) * 2;
    int lane = threadIdx.x & 63;
    const float4* O4 = (const float4*)oh;
    float4 o0 = O4[lane], o1 = O4[lane + 64], o2 = O4[lane + 128], o3 = O4[lane + 192];
    int r0 = rbase < VOCAB ? rbase : VOCAB - 1;          // clamp: safe dup loads
    int r1 = rbase + 1 < VOCAB ? rbase + 1 : VOCAB - 1;
    const float4* A0 = (const float4*)(W1_w + (size_t)r0 * H);
    const float4* A1 = (const float4*)(W1_w + (size_t)r1 * H);
    float a0 = 0.f, a1 = 0.f;
    #pragma unroll
    for (int i = 0; i < 4; i++) {
        int idx = lane + 64 * i;
        float4 ov = (i == 0) ? o0 : (i == 1) ? o1 : (i == 2) ? o2 : o3;
        float4 x0 = A0[idx], x1 = A1[idx];
        a0 += x0.x * ov.x + x0.y * ov.y + x0.z * ov.z + x0.w * ov.w;
        a1 += x1.x * ov.x + x1.y * ov.y + x1.z * ov.z + x1.w * ov.w;
    }
    a0 = wave_sum(a0);
    a1 = wave_sum(a1);
    if (lane == 0) {
        if (rbase < VOCAB)     out[rbase]     = a0 + W1_b[rbase];
        if (rbase + 1 < VOCAB) out[rbase + 1] = a1 + W1_b[rbase + 1];
    }
}

extern "C" void kernel_launch(void* const* d_in, const int* in_sizes, int n_in,
                              void* d_out, int out_size, void* d_ws, size_t ws_size,
                              hipStream_t stream) {
    const int*   x      = (const int*)  d_in[0];
    // d_in[1] entity_target: unused — new_mem[t] == h, scatter elides
    const float* emb    = (const float*)d_in[2];
    const float* W_ih   = (const float*)d_in[3];
    const float* W_hh   = (const float*)d_in[4];
    const float* b_ih   = (const float*)d_in[5];
    const float* b_hh   = (const float*)d_in[6];
    const float* h0     = (const float*)d_in[7];
    const float* c0     = (const float*)d_in[8];
    const float* hem    = (const float*)d_in[9];
    const float* Ws_w   = (const float*)d_in[10];
    // d_in[11] Ws_b: uniform shift of all scores — cancels in softmax
    const float* Wz_w   = (const float*)d_in[12];
    const float* Wz_b   = (const float*)d_in[13];
    const float* W2_w   = (const float*)d_in[14];
    const float* W2_b   = (const float*)d_in[15];
    const float* W1_w   = (const float*)d_in[16];
    const float* W1_b   = (const float*)d_in[17];

    float* out  = (float*)d_out;              // logits [V]
    float* zout = out + VOCAB;                // z_i    [1]
    float* pv   = out + VOCAB + 1;            // p_v    [M]

    float* ws = (float*)d_ws;
    float* h   = ws;                  // 1024
    float* v   = ws + 1024;           // 1024 (atomic acc, zeroed in k_lstm)
    float* sc  = ws + 2048;           // 16384
    float* dv  = ws + 18432;          // 1024 (atomic acc, zeroed in k_lstm)
    float* oh  = ws + 19456;          // 1024
    float* Mb  = ws + 20480;          // 256
    float* Sb  = ws + 20736;          // 256
    unsigned int* cnt = (unsigned int*)(ws + 20992);   // 2 (zeroed in k_lstm)
    float* db  = ws + 21504;          // 256*1024 partial d vectors

    k_lstm    <<<1024, 256, 0, stream>>>(x, emb, W_ih, W_hh, b_ih, b_hh, h0, c0,
                                         h, v, dv, cnt);
    k_mid     <<<320, 256, 0, stream>>>(h, W2_w, W2_b, oh, Ws_w, v);
    k_attn    <<<256, 1024, 0, stream>>>(hem, v, sc, db, Mb, Sb);
    k_fc1comb <<<COMB_BLOCKS + FC1_BLOCKS, 256, 0, stream>>>(
        oh, W1_w, W1_b, out, sc, db, Mb, Sb, pv, dv, h, Wz_w, Wz_b, zout, cnt);
}